// Round 9
// baseline (1603.991 us; speedup 1.0000x reference)
//
#include <hip/hip_runtime.h>
#include <hip/hip_bf16.h>
#include <hip/hip_cooperative_groups.h>
#include <stdint.h>

namespace cg = cooperative_groups;

// ---------------------------------------------------------------------------
// MambaEncoder forward. Round 10: dispatch-count reduction (49 -> 38).
//  - cvt hoisted out of the layer loop (1 dispatch for all 4 layers).
//  - scan1/2/3 fused into ONE cooperative kernel with grid.sync() between
//    phases (512 co-resident blocks; phase math verbatim from r8 = verified).
// GEMM inner loop = r8 (BK=64, XOR swizzle, 0 bank conflicts).
// ---------------------------------------------------------------------------

#define SEQ     4096
#define DMODEL  1024
#define DINNER  2048
#define NSTATE  16
#define DTRANK  64
#define NLAYERS 4
#define LC      64    // scan chunk length
#define NC      64    // number of chunks (SEQ/LC)

typedef __attribute__((ext_vector_type(8))) short short8v;   // 8 bf16 (4 VGPRs)
typedef __attribute__((ext_vector_type(4))) float f32x4;
typedef __hip_bfloat16 bf16;

__device__ __forceinline__ float b2f(unsigned short x) {
    unsigned int u = ((unsigned int)x) << 16;
    return __builtin_bit_cast(float, u);
}

// ------------------------------------------------------------ async g->LDS 16B
__device__ __forceinline__ void gld16(const void* gsrc, void* ldst) {
    __builtin_amdgcn_global_load_lds(
        (const __attribute__((address_space(1))) void*)gsrc,
        (__attribute__((address_space(3))) void*)ldst, 16, 0, 0);
}

// ---------------------------------------------------------------- block sum
__device__ __forceinline__ float block_sum(float v, float* red, int nwaves) {
    #pragma unroll
    for (int o = 32; o > 0; o >>= 1) v += __shfl_down(v, o, 64);
    int lane = threadIdx.x & 63, w = threadIdx.x >> 6;
    __syncthreads();
    if (lane == 0) red[w] = v;
    __syncthreads();
    float s = red[0];
    for (int i = 1; i < nwaves; i++) s += red[i];
    return s;
}

// ------------------------------------------------------------- layernorm row
template<int WIDTH, typename OutT>
__global__ void ln_kernel(const float* __restrict__ X, const float* __restrict__ X2,
                          const float* __restrict__ g, const float* __restrict__ bta,
                          OutT* __restrict__ out, float eps) {
    constexpr int E = WIDTH / 256;
    __shared__ float red[4];
    int s = blockIdx.x, tid = threadIdx.x;
    size_t base = (size_t)s * WIDTH;
    float v[E]; float sum = 0.f;
    #pragma unroll
    for (int i = 0; i < E; i++) {
        int c = tid + i * 256;
        float t = X[base + c];
        if (X2) t += X2[base + c];
        v[i] = t; sum += t;
    }
    float mu = block_sum(sum, red, 4) * (1.f / WIDTH);
    float sq = 0.f;
    #pragma unroll
    for (int i = 0; i < E; i++) { float d = v[i] - mu; sq += d * d; }
    float var = block_sum(sq, red, 4) * (1.f / WIDTH);
    float rstd = rsqrtf(var + eps);
    #pragma unroll
    for (int i = 0; i < E; i++) {
        int c = tid + i * 256;
        float r = (v[i] - mu) * rstd * g[c] + bta[c];
        out[base + c] = (OutT)r;
    }
}

// --------------------------------------------------- outnorm + silu(z) gate
__global__ void outnorm_silu_kernel(const float* __restrict__ y, const bf16* __restrict__ xz,
                                    const float* __restrict__ g, const float* __restrict__ bta,
                                    bf16* __restrict__ p_bf, float eps) {
    constexpr int WIDTH = DINNER, E = WIDTH / 256;
    __shared__ float red[4];
    int s = blockIdx.x, tid = threadIdx.x;
    size_t base = (size_t)s * WIDTH;
    const unsigned short* xzu = (const unsigned short*)xz;
    float v[E]; float sum = 0.f;
    #pragma unroll
    for (int i = 0; i < E; i++) { int c = tid + i * 256; v[i] = y[base + c]; sum += v[i]; }
    float mu = block_sum(sum, red, 4) * (1.f / WIDTH);
    float sq = 0.f;
    #pragma unroll
    for (int i = 0; i < E; i++) { float d = v[i] - mu; sq += d * d; }
    float var = block_sum(sq, red, 4) * (1.f / WIDTH);
    float rstd = rsqrtf(var + eps);
    #pragma unroll
    for (int i = 0; i < E; i++) {
        int c = tid + i * 256;
        float ln = (v[i] - mu) * rstd * g[c] + bta[c];
        float z = b2f(xzu[(size_t)s * (2 * DINNER) + DINNER + c]);
        float sig = 1.f / (1.f + __expf(-z));
        p_bf[base + c] = __float2bfloat16(ln * (z * sig));
    }
}

// ------------------------------------------------------- depthwise conv, k=3
__global__ void conv_kernel(const bf16* __restrict__ xz, const float* __restrict__ cw,
                            const float* __restrict__ cb, bf16* __restrict__ u_bf) {
    int t = blockIdx.x * 256 + threadIdx.x;     // SEQ * 512
    int s = t >> 9, c = (t & 511) * 4;
    size_t row = (size_t)s * (2 * DINNER);
    const unsigned short* xp = (const unsigned short*)xz;
    ushort4 z4 = {0, 0, 0, 0};
    ushort4 v0 = *(const ushort4*)(xp + row + c);
    ushort4 vm = (s > 0)       ? *(const ushort4*)(xp + row - 2 * DINNER + c) : z4;
    ushort4 vp = (s < SEQ - 1) ? *(const ushort4*)(xp + row + 2 * DINNER + c) : z4;
    unsigned short o[4];
    float x0[4] = {b2f(v0.x), b2f(v0.y), b2f(v0.z), b2f(v0.w)};
    float xm[4] = {b2f(vm.x), b2f(vm.y), b2f(vm.z), b2f(vm.w)};
    float xp4[4] = {b2f(vp.x), b2f(vp.y), b2f(vp.z), b2f(vp.w)};
    #pragma unroll
    for (int i = 0; i < 4; i++) {
        int ch = c + i;
        float u = cw[ch * 3 + 0] * xm[i] + cw[ch * 3 + 1] * x0[i]
                + cw[ch * 3 + 2] * xp4[i] + cb[ch];
        o[i] = __builtin_bit_cast(unsigned short, __float2bfloat16(u));
    }
    *(ushort4*)((unsigned short*)u_bf + (size_t)s * DINNER + c) = {o[0], o[1], o[2], o[3]};
}

// ----------------------- fused fp32 -> bf16 cvt, ALL FOUR LAYERS, one launch
#define CN0 (2 * DINNER * DMODEL)   // per-layer in_proj elems
#define CN1 (DMODEL * DINNER)       // per-layer out_proj
#define CN2 (96 * DINNER)           // per-layer deltaBC
#define CN3 (DINNER * DTRANK)       // per-layer dt_proj
#define S0 (4 * CN0)                // 16777216
#define S1 (4 * CN1)                //  8388608
#define S2 (4 * CN2)                //   786432
#define S3 (4 * CN3)                //   524288
__global__ void cvt4_kernel(const float* __restrict__ w0, const float* __restrict__ w1,
                            const float* __restrict__ w2, const float* __restrict__ w3,
                            bf16* __restrict__ o0, bf16* __restrict__ o1,
                            bf16* __restrict__ o2, bf16* __restrict__ o3) {
    size_t i = (size_t)(blockIdx.x * 256 + threadIdx.x) * 4;
    const float* src; bf16* dst;
    if (i < S0)                { src = w0; dst = o0; }
    else if (i < S0 + S1)      { src = w1; dst = o1; i -= S0; }
    else if (i < S0 + S1 + S2) { src = w2; dst = o2; i -= S0 + S1; }
    else                       { src = w3; dst = o3; i -= S0 + S1 + S2; }
    float4 v = *(const float4*)(src + i);
    __hip_bfloat162 t0, t1;
    t0.x = __float2bfloat16(v.x); t0.y = __float2bfloat16(v.y);
    t1.x = __float2bfloat16(v.z); t1.y = __float2bfloat16(v.w);
    __hip_bfloat162* o = (__hip_bfloat162*)(dst + i);
    o[0] = t0; o[1] = t1;
}

// --------------------------------------------------------- bf16 MFMA GEMM
// MODE 0: +bias, bf16 out (in_proj)   MODE 1: split-K partial, N=96 (dbc)
// MODE 2: +bias, softplus, f32 out    MODE 3: +bias, +res, f32 out (out_proj)
// BK=64 + both-sides XOR chunk swizzle (r8-verified: 0 bank conflicts).
template<int MODE>
__global__ __launch_bounds__(256, 3)
void mfma_gemm(const bf16* __restrict__ A, int lda,
               const bf16* __restrict__ W, int ldw,
               const float* __restrict__ bias,
               float* __restrict__ C, int ldc,
               const float* __restrict__ res,
               bf16* __restrict__ Cbf,
               int M, int N, int K) {
    __shared__ __attribute__((aligned(16))) short sA[128][64];
    __shared__ __attribute__((aligned(16))) short sB[128][64];
    int tid = threadIdx.x;
    int lane = tid & 63, w = tid >> 6;
    int wm = w >> 1, wn = w & 1;
    int m0 = blockIdx.x * 128, n0 = blockIdx.y * 128;
    int r16 = lane & 15, quad = lane >> 4;

    if (MODE == 1) {       // split-K over blockIdx.z
        int kz = blockIdx.z;
        A += (size_t)kz * K;
        W += (size_t)kz * K;
        C += (size_t)kz * M * 96;
    }

    f32x4 acc[4][4] = {};

    for (int k0 = 0; k0 < K; k0 += 64) {
        __syncthreads();
        #pragma unroll
        for (int j = 0; j < 4; j++) {
            int idx = j * 256 + tid;
            int row = idx >> 3;
            int csrc = (idx & 7) ^ (row & 7);
            gld16(A + (size_t)(m0 + row) * lda + k0 + csrc * 8,
                  (char*)&sA[0][0] + j * 4096 + w * 1024);
            int nr = n0 + row; if (nr > N - 1) nr = N - 1;   // clamp (MODE 1)
            gld16(W + (size_t)nr * ldw + k0 + csrc * 8,
                  (char*)&sB[0][0] + j * 4096 + w * 1024);
        }
        __syncthreads();
        #pragma unroll
        for (int s = 0; s < 2; s++) {
            short8v aF[4], bF[4];
            #pragma unroll
            for (int mi = 0; mi < 4; mi++)
                aF[mi] = *(const short8v*)
                    &sA[wm * 64 + mi * 16 + r16][((s * 4 + quad) ^ (r16 & 7)) * 8];
            #pragma unroll
            for (int ni = 0; ni < 4; ni++)
                bF[ni] = *(const short8v*)
                    &sB[wn * 64 + ni * 16 + r16][((s * 4 + quad) ^ (r16 & 7)) * 8];
            #pragma unroll
            for (int mi = 0; mi < 4; mi++)
                #pragma unroll
                for (int ni = 0; ni < 4; ni++)
                    acc[mi][ni] = __builtin_amdgcn_mfma_f32_16x16x32_bf16(
                        aF[mi], bF[ni], acc[mi][ni], 0, 0, 0);
        }
    }

    #pragma unroll
    for (int mi = 0; mi < 4; mi++) {
        #pragma unroll
        for (int ni = 0; ni < 4; ni++) {
            f32x4 a = acc[mi][ni];
            int col = n0 + wn * 64 + ni * 16 + r16;
            int rbase = m0 + wm * 64 + mi * 16 + quad * 4;
            #pragma unroll
            for (int r = 0; r < 4; r++) {
                int row = rbase + r;
                float v = a[r];
                if (MODE == 0 || MODE == 2 || MODE == 3) v += bias[col];
                if (MODE == 2) v = (v > 20.f) ? v : log1pf(__expf(v));
                if (MODE == 3) v += res[(size_t)row * ldc + col];
                if (MODE == 1) {
                    if (col < 96) C[(size_t)row * 96 + col] = v;
                } else if (MODE == 0) {
                    Cbf[(size_t)row * ldc + col] = __float2bfloat16(v);
                } else {
                    C[(size_t)row * ldc + col] = v;
                }
            }
        }
    }
}

// -------------------------------------------- reduce split-K partials of dbc
__global__ void reduce_dbc_kernel(const float* __restrict__ p, float* __restrict__ dbc,
                                  bf16* __restrict__ dbc_bf) {
    int i = blockIdx.x * 256 + threadIdx.x;      // SEQ*96
    const int SP = SEQ * 96;
    float v = p[i] + p[i + SP] + p[i + 2 * SP] + p[i + 3 * SP];
    dbc[i] = v;
    int row = i / 96, c = i - row * 96;
    if (c < DTRANK) dbc_bf[(size_t)row * DTRANK + c] = __float2bfloat16(v);
}

// --------------------------------------------------- exp-chain detection
__device__ __forceinline__ bool a_is_neg_integers(const float* a) {
    bool fast = true;
    #pragma unroll
    for (int n = 0; n < NSTATE; n++)
        fast = fast && (__builtin_fabsf(a[n] + (float)(n + 1)) < 1e-3f * (n + 1));
    return fast;
}

// ---------------------------------------------------------------------------
// Fused 3-phase selective scan, ONE cooperative dispatch (was 3 kernels).
// Grid: (NC=64, DINNER/256=8) = 512 blocks x 256 thr, all co-resident.
// Phase 1 = scan1 (per-chunk h_end/dsum, h from 0)       [all blocks]
// grid.sync()
// Phase 2 = scan2 (serial chunk-prefix -> hinit)         [flat bid < 128]
// grid.sync()
// Phase 3 = scan3 (y, h from hinit; reuses a[]/fast/d)   [all blocks]
// Phase bodies are verbatim r8 scan kernels (verified) -> identical math.
// ---------------------------------------------------------------------------
__global__ __launch_bounds__(256)
void scan_fused_kernel(float* __restrict__ delta_y, const bf16* __restrict__ u,
                       const float* __restrict__ dbc, const float* __restrict__ A_log,
                       const float* __restrict__ Dp,
                       float* __restrict__ h_end, float* __restrict__ dsum,
                       float* __restrict__ hinit) {
    cg::grid_group grid = cg::this_grid();
    int k = blockIdx.x, tid = threadIdx.x;
    int d = blockIdx.y * 256 + tid;
    int s0 = k * LC;
    float a[NSTATE];
    #pragma unroll
    for (int n = 0; n < NSTATE; n++) a[n] = -__expf(A_log[(size_t)d * NSTATE + n]);
    bool fast = a_is_neg_integers(a);
    float dpv = Dp[d];

    // ---------------- phase 1 (scan1)
    {
        const float* dp = delta_y + (size_t)s0 * DINNER + d;
        const unsigned short* up = (const unsigned short*)u + (size_t)s0 * DINNER + d;
        const float* br = dbc + (size_t)s0 * 96 + DTRANK;
        float h[NSTATE] = {};
        float ds = 0.f;
        if (fast) {
            #pragma unroll 2
            for (int r = 0; r < LC; r++) {
                float dl = *dp;
                float uu = b2f(*up);
                float4 b0 = *(const float4*)(br);
                float4 b1 = *(const float4*)(br + 4);
                float4 b2 = *(const float4*)(br + 8);
                float4 b3 = *(const float4*)(br + 12);
                float Bv[NSTATE] = {b0.x, b0.y, b0.z, b0.w, b1.x, b1.y, b1.z, b1.w,
                                    b2.x, b2.y, b2.z, b2.w, b3.x, b3.y, b3.z, b3.w};
                ds += dl;
                float du = dl * uu;
                float g = __expf(-dl);
                float fac = 1.f;
                #pragma unroll
                for (int n = 0; n < NSTATE; n++) {
                    fac *= g;
                    h[n] = fac * h[n] + du * Bv[n];
                }
                dp += DINNER; up += DINNER; br += 96;
            }
        } else {
            #pragma unroll 2
            for (int r = 0; r < LC; r++) {
                float dl = *dp;
                float uu = b2f(*up);
                float4 b0 = *(const float4*)(br);
                float4 b1 = *(const float4*)(br + 4);
                float4 b2 = *(const float4*)(br + 8);
                float4 b3 = *(const float4*)(br + 12);
                float Bv[NSTATE] = {b0.x, b0.y, b0.z, b0.w, b1.x, b1.y, b1.z, b1.w,
                                    b2.x, b2.y, b2.z, b2.w, b3.x, b3.y, b3.z, b3.w};
                ds += dl;
                float du = dl * uu;
                #pragma unroll
                for (int n = 0; n < NSTATE; n++)
                    h[n] = __expf(dl * a[n]) * h[n] + du * Bv[n];
                dp += DINNER; up += DINNER; br += 96;
            }
        }
        #pragma unroll
        for (int n = 0; n < NSTATE; n++)
            h_end[((size_t)k * NSTATE + n) * DINNER + d] = h[n];
        dsum[(size_t)k * DINNER + d] = ds;
    }

    grid.sync();

    // ---------------- phase 2 (scan2) on first 128 flat blocks
    {
        int bid = blockIdx.y * NC + k;
        if (bid < (DINNER * NSTATE) / 256 / 64) { /* 32768/256/64? no */ }
        if (bid < 128) {
            int id = bid * 256 + tid;                // [0, 32768)
            int d2 = id & (DINNER - 1), n2 = id >> 11;
            float a2 = -__expf(A_log[(size_t)d2 * NSTATE + n2]);
            float h = 0.f;
            #pragma unroll 4
            for (int k2 = 0; k2 < NC; k2++) {
                size_t off = ((size_t)k2 * NSTATE + n2) * DINNER + d2;
                hinit[off] = h;
                h = __expf(a2 * dsum[(size_t)k2 * DINNER + d2]) * h + h_end[off];
            }
        }
    }

    grid.sync();

    // ---------------- phase 3 (scan3); reuse a[], fast, dpv
    {
        float h[NSTATE];
        #pragma unroll
        for (int n = 0; n < NSTATE; n++)
            h[n] = hinit[((size_t)k * NSTATE + n) * DINNER + d];
        float* dp = delta_y + (size_t)s0 * DINNER + d;
        const unsigned short* up = (const unsigned short*)u + (size_t)s0 * DINNER + d;
        const float* br = dbc + (size_t)s0 * 96 + DTRANK;
        if (fast) {
            #pragma unroll 2
            for (int r = 0; r < LC; r++) {
                float dl = *dp;
                float uu = b2f(*up);
                float4 b0 = *(const float4*)(br);
                float4 b1 = *(const float4*)(br + 4);
                float4 b2 = *(const float4*)(br + 8);
                float4 b3 = *(const float4*)(br + 12);
                float4 c0 = *(const float4*)(br + 16);
                float4 c1 = *(const float4*)(br + 20);
                float4 c2 = *(const float4*)(br + 24);
                float4 c3 = *(const float4*)(br + 28);
                float Bv[NSTATE] = {b0.x, b0.y, b0.z, b0.w, b1.x, b1.y, b1.z, b1.w,
                                    b2.x, b2.y, b2.z, b2.w, b3.x, b3.y, b3.z, b3.w};
                float Cv[NSTATE] = {c0.x, c0.y, c0.z, c0.w, c1.x, c1.y, c1.z, c1.w,
                                    c2.x, c2.y, c2.z, c2.w, c3.x, c3.y, c3.z, c3.w};
                float du = dl * uu;
                float g = __expf(-dl);
                float y = uu * dpv;
                float fac = 1.f;
                #pragma unroll
                for (int n = 0; n < NSTATE; n++) {
                    fac *= g;
                    h[n] = fac * h[n] + du * Bv[n];
                    y += h[n] * Cv[n];
                }
                *dp = y;
                dp += DINNER; up += DINNER; br += 96;
            }
        } else {
            #pragma unroll 2
            for (int r = 0; r < LC; r++) {
                float dl = *dp;
                float uu = b2f(*up);
                float4 b0 = *(const float4*)(br);
                float4 b1 = *(const float4*)(br + 4);
                float4 b2 = *(const float4*)(br + 8);
                float4 b3 = *(const float4*)(br + 12);
                float4 c0 = *(const float4*)(br + 16);
                float4 c1 = *(const float4*)(br + 20);
                float4 c2 = *(const float4*)(br + 24);
                float4 c3 = *(const float4*)(br + 28);
                float Bv[NSTATE] = {b0.x, b0.y, b0.z, b0.w, b1.x, b1.y, b1.z, b1.w,
                                    b2.x, b2.y, b2.z, b2.w, b3.x, b3.y, b3.z, b3.w};
                float Cv[NSTATE] = {c0.x, c0.y, c0.z, c0.w, c1.x, c1.y, c1.z, c1.w,
                                    c2.x, c2.y, c2.z, c2.w, c3.x, c3.y, c3.z, c3.w};
                float du = dl * uu;
                float y = uu * dpv;
                #pragma unroll
                for (int n = 0; n < NSTATE; n++) {
                    h[n] = __expf(dl * a[n]) * h[n] + du * Bv[n];
                    y += h[n] * Cv[n];
                }
                *dp = y;
                dp += DINNER; up += DINNER; br += 96;
            }
        }
    }
}

// ---------------------------------------------------------------------------
extern "C" void kernel_launch(void* const* d_in, const int* in_sizes, int n_in,
                              void* d_out, int out_size, void* d_ws, size_t ws_size,
                              hipStream_t stream) {
    const float* x         = (const float*)d_in[0];
    const float* pos       = (const float*)d_in[1];
    const float* ln_g      = (const float*)d_in[2];
    const float* ln_b      = (const float*)d_in[3];
    const float* innorm_g  = (const float*)d_in[4];
    const float* innorm_b  = (const float*)d_in[5];
    const float* in_proj_w = (const float*)d_in[6];
    const float* in_proj_b = (const float*)d_in[7];
    const float* conv_w    = (const float*)d_in[8];
    const float* conv_b    = (const float*)d_in[9];
    const float* deltaBC_w = (const float*)d_in[10];
    const float* dt_proj_w = (const float*)d_in[11];
    const float* dt_proj_b = (const float*)d_in[12];
    const float* A_log     = (const float*)d_in[13];
    const float* Dp        = (const float*)d_in[14];
    const float* outnorm_g = (const float*)d_in[15];
    const float* outnorm_b = (const float*)d_in[16];
    const float* out_proj_w= (const float*)d_in[17];
    const float* out_proj_b= (const float*)d_in[18];

    float* enc = (float*)d_out;
    char* ws = (char*)d_ws;
    const size_t MB = 1024 * 1024;
    bf16*  h_bf   = (bf16*) (ws + 0);            //  8 MB [S,d]  (aliased w/ p_bf)
    bf16*  p_bf   = (bf16*) (ws + 0);            // 16 MB [S,di]
    bf16*  xz_bf  = (bf16*) (ws + 16 * MB);      // 32 MB [S,2di]
    float* dlt    = (float*)(ws + 48 * MB);      // 32 MB delta -> y (in place)
    float* dbcp   = (float*)(ws + 48 * MB);      //  6 MB splitK partials (alias dlt)
    bf16*  u_bf   = (bf16*) (ws + 80 * MB);      // 16 MB [S,di]
    float* dbc    = (float*)(ws + 96 * MB);      // 1.5MB [S,96]
    bf16*  dbc_bf = (bf16*) (ws + 98 * MB);      // 0.5MB [S,64]
    float* h_end  = (float*)(ws + 99 * MB);      //  8 MB [NC,n,di]
    float* hinit  = (float*)(ws + 107 * MB);     //  8 MB [NC,n,di]
    float* dsum   = (float*)(ws + 115 * MB);     // 0.5MB [NC,di]
    bf16*  w_in   = (bf16*) (ws + 116 * MB);     // 32 MB (4 layers x 8)
    bf16*  w_out  = (bf16*) (ws + 148 * MB);     // 16 MB (4 x 4)
    bf16*  w_dbc  = (bf16*) (ws + 164 * MB);     // 1.5 MB (4 x .375)
    bf16*  w_dt   = (bf16*) (ws + 166 * MB);     //  1 MB (4 x .25) -> 167 MB total

    // weight conversion for ALL layers, one dispatch
    cvt4_kernel<<<(S0 + S1 + S2 + S3) / 1024, 256, 0, stream>>>(
        in_proj_w, out_proj_w, deltaBC_w, dt_proj_w, w_in, w_out, w_dbc, w_dt);

    ln_kernel<DMODEL, float><<<SEQ, 256, 0, stream>>>(x, pos, ln_g, ln_b, enc, 1e-6f);

    for (int L = 0; L < NLAYERS; L++) {
        const float* Al  = A_log + (size_t)L * DINNER * NSTATE;
        const float* Dpl = Dp + (size_t)L * DINNER;

        ln_kernel<DMODEL, bf16><<<SEQ, 256, 0, stream>>>(enc, nullptr, innorm_g + L * DMODEL,
                                                         innorm_b + L * DMODEL, h_bf, 1e-5f);
        // xz = h @ in_proj_w^T + b  -> bf16   [4096 x 4096], K=1024
        mfma_gemm<0><<<dim3(32, 32), 256, 0, stream>>>(
            h_bf, DMODEL, w_in + (size_t)L * CN0, DMODEL, in_proj_b + (size_t)L * 2 * DINNER,
            nullptr, 2 * DINNER, nullptr, xz_bf, SEQ, 2 * DINNER, DMODEL);
        conv_kernel<<<(SEQ * 512) / 256, 256, 0, stream>>>(
            xz_bf, conv_w + (size_t)L * DINNER * 3, conv_b + L * DINNER, u_bf);
        // dbc = u @ deltaBC_w^T   split-K x4, K=512 each
        mfma_gemm<1><<<dim3(32, 1, 4), 256, 0, stream>>>(
            u_bf, DINNER, w_dbc + (size_t)L * CN2, DINNER, nullptr,
            dbcp, 96, nullptr, nullptr, SEQ, 96, 512);
        reduce_dbc_kernel<<<(SEQ * 96) / 256, 256, 0, stream>>>(dbcp, dbc, dbc_bf);
        // delta = softplus(dbc[:,:64] @ dt_proj_w^T + b)   [4096 x 2048], K=64
        mfma_gemm<2><<<dim3(32, 16), 256, 0, stream>>>(
            dbc_bf, DTRANK, w_dt + (size_t)L * CN3, DTRANK, dt_proj_b + L * DINNER,
            dlt, DINNER, nullptr, nullptr, SEQ, DINNER, DTRANK);
        // fused 3-phase selective scan (cooperative); y overwrites dlt
        {
            void* args[] = {(void*)&dlt, (void*)&u_bf, (void*)&dbc, (void*)&Al,
                            (void*)&Dpl, (void*)&h_end, (void*)&dsum, (void*)&hinit};
            hipLaunchCooperativeKernel((const void*)scan_fused_kernel,
                                       dim3(NC, DINNER / 256), dim3(256, 1, 1),
                                       args, 0, stream);
        }
        outnorm_silu_kernel<<<SEQ, 256, 0, stream>>>(dlt, xz_bf, outnorm_g + L * DINNER,
                                                     outnorm_b + L * DINNER, p_bf, 1e-5f);
        // enc = p @ out_proj_w^T + b + enc   [4096 x 1024], K=2048
        mfma_gemm<3><<<dim3(32, 8), 256, 0, stream>>>(
            p_bf, DINNER, w_out + (size_t)L * CN1, DINNER, out_proj_b + L * DMODEL,
            enc, DMODEL, enc, nullptr, SEQ, DMODEL, DINNER);
    }
}

// Round 10
// 1077.704 us; speedup vs baseline: 1.4883x; 1.4883x over previous
//
#include <hip/hip_runtime.h>
#include <hip/hip_bf16.h>
#include <stdint.h>

// ---------------------------------------------------------------------------
// MambaEncoder forward. Round 11: r9's cooperative scan fusion REVERTED
// (grid.sync costs ~55-60us each on MI355X's 8-XCD fabric; kernel-boundary
// sync is cheaper). Keeps r9's all-layer cvt4 hoist (1 dispatch for all
// weights) + r8's verified GEMM (BK=64, XOR swizzle, 0 conflicts) and
// LDS-free scans. r8 baseline: 1093 us.
// ---------------------------------------------------------------------------

#define SEQ     4096
#define DMODEL  1024
#define DINNER  2048
#define NSTATE  16
#define DTRANK  64
#define NLAYERS 4
#define LC      64    // scan chunk length
#define NC      64    // number of chunks (SEQ/LC)

typedef __attribute__((ext_vector_type(8))) short short8v;   // 8 bf16 (4 VGPRs)
typedef __attribute__((ext_vector_type(4))) float f32x4;
typedef __hip_bfloat16 bf16;

__device__ __forceinline__ float b2f(unsigned short x) {
    unsigned int u = ((unsigned int)x) << 16;
    return __builtin_bit_cast(float, u);
}

// ------------------------------------------------------------ async g->LDS 16B
__device__ __forceinline__ void gld16(const void* gsrc, void* ldst) {
    __builtin_amdgcn_global_load_lds(
        (const __attribute__((address_space(1))) void*)gsrc,
        (__attribute__((address_space(3))) void*)ldst, 16, 0, 0);
}

// ---------------------------------------------------------------- block sum
__device__ __forceinline__ float block_sum(float v, float* red, int nwaves) {
    #pragma unroll
    for (int o = 32; o > 0; o >>= 1) v += __shfl_down(v, o, 64);
    int lane = threadIdx.x & 63, w = threadIdx.x >> 6;
    __syncthreads();
    if (lane == 0) red[w] = v;
    __syncthreads();
    float s = red[0];
    for (int i = 1; i < nwaves; i++) s += red[i];
    return s;
}

// ------------------------------------------------------------- layernorm row
template<int WIDTH, typename OutT>
__global__ void ln_kernel(const float* __restrict__ X, const float* __restrict__ X2,
                          const float* __restrict__ g, const float* __restrict__ bta,
                          OutT* __restrict__ out, float eps) {
    constexpr int E = WIDTH / 256;
    __shared__ float red[4];
    int s = blockIdx.x, tid = threadIdx.x;
    size_t base = (size_t)s * WIDTH;
    float v[E]; float sum = 0.f;
    #pragma unroll
    for (int i = 0; i < E; i++) {
        int c = tid + i * 256;
        float t = X[base + c];
        if (X2) t += X2[base + c];
        v[i] = t; sum += t;
    }
    float mu = block_sum(sum, red, 4) * (1.f / WIDTH);
    float sq = 0.f;
    #pragma unroll
    for (int i = 0; i < E; i++) { float d = v[i] - mu; sq += d * d; }
    float var = block_sum(sq, red, 4) * (1.f / WIDTH);
    float rstd = rsqrtf(var + eps);
    #pragma unroll
    for (int i = 0; i < E; i++) {
        int c = tid + i * 256;
        float r = (v[i] - mu) * rstd * g[c] + bta[c];
        out[base + c] = (OutT)r;
    }
}

// --------------------------------------------------- outnorm + silu(z) gate
__global__ void outnorm_silu_kernel(const float* __restrict__ y, const bf16* __restrict__ xz,
                                    const float* __restrict__ g, const float* __restrict__ bta,
                                    bf16* __restrict__ p_bf, float eps) {
    constexpr int WIDTH = DINNER, E = WIDTH / 256;
    __shared__ float red[4];
    int s = blockIdx.x, tid = threadIdx.x;
    size_t base = (size_t)s * WIDTH;
    const unsigned short* xzu = (const unsigned short*)xz;
    float v[E]; float sum = 0.f;
    #pragma unroll
    for (int i = 0; i < E; i++) { int c = tid + i * 256; v[i] = y[base + c]; sum += v[i]; }
    float mu = block_sum(sum, red, 4) * (1.f / WIDTH);
    float sq = 0.f;
    #pragma unroll
    for (int i = 0; i < E; i++) { float d = v[i] - mu; sq += d * d; }
    float var = block_sum(sq, red, 4) * (1.f / WIDTH);
    float rstd = rsqrtf(var + eps);
    #pragma unroll
    for (int i = 0; i < E; i++) {
        int c = tid + i * 256;
        float ln = (v[i] - mu) * rstd * g[c] + bta[c];
        float z = b2f(xzu[(size_t)s * (2 * DINNER) + DINNER + c]);
        float sig = 1.f / (1.f + __expf(-z));
        p_bf[base + c] = __float2bfloat16(ln * (z * sig));
    }
}

// ------------------------------------------------------- depthwise conv, k=3
__global__ void conv_kernel(const bf16* __restrict__ xz, const float* __restrict__ cw,
                            const float* __restrict__ cb, bf16* __restrict__ u_bf) {
    int t = blockIdx.x * 256 + threadIdx.x;     // SEQ * 512
    int s = t >> 9, c = (t & 511) * 4;
    size_t row = (size_t)s * (2 * DINNER);
    const unsigned short* xp = (const unsigned short*)xz;
    ushort4 z4 = {0, 0, 0, 0};
    ushort4 v0 = *(const ushort4*)(xp + row + c);
    ushort4 vm = (s > 0)       ? *(const ushort4*)(xp + row - 2 * DINNER + c) : z4;
    ushort4 vp = (s < SEQ - 1) ? *(const ushort4*)(xp + row + 2 * DINNER + c) : z4;
    unsigned short o[4];
    float x0[4] = {b2f(v0.x), b2f(v0.y), b2f(v0.z), b2f(v0.w)};
    float xm[4] = {b2f(vm.x), b2f(vm.y), b2f(vm.z), b2f(vm.w)};
    float xp4[4] = {b2f(vp.x), b2f(vp.y), b2f(vp.z), b2f(vp.w)};
    #pragma unroll
    for (int i = 0; i < 4; i++) {
        int ch = c + i;
        float u = cw[ch * 3 + 0] * xm[i] + cw[ch * 3 + 1] * x0[i]
                + cw[ch * 3 + 2] * xp4[i] + cb[ch];
        o[i] = __builtin_bit_cast(unsigned short, __float2bfloat16(u));
    }
    *(ushort4*)((unsigned short*)u_bf + (size_t)s * DINNER + c) = {o[0], o[1], o[2], o[3]};
}

// ----------------------- fused fp32 -> bf16 cvt, ALL FOUR LAYERS, one launch
#define CN0 (2 * DINNER * DMODEL)   // per-layer in_proj elems
#define CN1 (DMODEL * DINNER)       // per-layer out_proj
#define CN2 (96 * DINNER)           // per-layer deltaBC
#define CN3 (DINNER * DTRANK)       // per-layer dt_proj
#define S0 (4 * CN0)                // 16777216
#define S1 (4 * CN1)                //  8388608
#define S2 (4 * CN2)                //   786432
#define S3 (4 * CN3)                //   524288
__global__ void cvt4_kernel(const float* __restrict__ w0, const float* __restrict__ w1,
                            const float* __restrict__ w2, const float* __restrict__ w3,
                            bf16* __restrict__ o0, bf16* __restrict__ o1,
                            bf16* __restrict__ o2, bf16* __restrict__ o3) {
    size_t i = (size_t)(blockIdx.x * 256 + threadIdx.x) * 4;
    const float* src; bf16* dst;
    if (i < S0)                { src = w0; dst = o0; }
    else if (i < S0 + S1)      { src = w1; dst = o1; i -= S0; }
    else if (i < S0 + S1 + S2) { src = w2; dst = o2; i -= S0 + S1; }
    else                       { src = w3; dst = o3; i -= S0 + S1 + S2; }
    float4 v = *(const float4*)(src + i);
    __hip_bfloat162 t0, t1;
    t0.x = __float2bfloat16(v.x); t0.y = __float2bfloat16(v.y);
    t1.x = __float2bfloat16(v.z); t1.y = __float2bfloat16(v.w);
    __hip_bfloat162* o = (__hip_bfloat162*)(dst + i);
    o[0] = t0; o[1] = t1;
}

// --------------------------------------------------------- bf16 MFMA GEMM
// MODE 0: +bias, bf16 out (in_proj)   MODE 1: split-K partial, N=96 (dbc)
// MODE 2: +bias, softplus, f32 out    MODE 3: +bias, +res, f32 out (out_proj)
// BK=64 + both-sides XOR chunk swizzle (r8-verified: 0 bank conflicts).
template<int MODE>
__global__ __launch_bounds__(256, 3)
void mfma_gemm(const bf16* __restrict__ A, int lda,
               const bf16* __restrict__ W, int ldw,
               const float* __restrict__ bias,
               float* __restrict__ C, int ldc,
               const float* __restrict__ res,
               bf16* __restrict__ Cbf,
               int M, int N, int K) {
    __shared__ __attribute__((aligned(16))) short sA[128][64];
    __shared__ __attribute__((aligned(16))) short sB[128][64];
    int tid = threadIdx.x;
    int lane = tid & 63, w = tid >> 6;
    int wm = w >> 1, wn = w & 1;
    int m0 = blockIdx.x * 128, n0 = blockIdx.y * 128;
    int r16 = lane & 15, quad = lane >> 4;

    if (MODE == 1) {       // split-K over blockIdx.z
        int kz = blockIdx.z;
        A += (size_t)kz * K;
        W += (size_t)kz * K;
        C += (size_t)kz * M * 96;
    }

    f32x4 acc[4][4] = {};

    for (int k0 = 0; k0 < K; k0 += 64) {
        __syncthreads();
        #pragma unroll
        for (int j = 0; j < 4; j++) {
            int idx = j * 256 + tid;
            int row = idx >> 3;
            int csrc = (idx & 7) ^ (row & 7);
            gld16(A + (size_t)(m0 + row) * lda + k0 + csrc * 8,
                  (char*)&sA[0][0] + j * 4096 + w * 1024);
            int nr = n0 + row; if (nr > N - 1) nr = N - 1;   // clamp (MODE 1)
            gld16(W + (size_t)nr * ldw + k0 + csrc * 8,
                  (char*)&sB[0][0] + j * 4096 + w * 1024);
        }
        __syncthreads();
        #pragma unroll
        for (int s = 0; s < 2; s++) {
            short8v aF[4], bF[4];
            #pragma unroll
            for (int mi = 0; mi < 4; mi++)
                aF[mi] = *(const short8v*)
                    &sA[wm * 64 + mi * 16 + r16][((s * 4 + quad) ^ (r16 & 7)) * 8];
            #pragma unroll
            for (int ni = 0; ni < 4; ni++)
                bF[ni] = *(const short8v*)
                    &sB[wn * 64 + ni * 16 + r16][((s * 4 + quad) ^ (r16 & 7)) * 8];
            #pragma unroll
            for (int mi = 0; mi < 4; mi++)
                #pragma unroll
                for (int ni = 0; ni < 4; ni++)
                    acc[mi][ni] = __builtin_amdgcn_mfma_f32_16x16x32_bf16(
                        aF[mi], bF[ni], acc[mi][ni], 0, 0, 0);
        }
    }

    #pragma unroll
    for (int mi = 0; mi < 4; mi++) {
        #pragma unroll
        for (int ni = 0; ni < 4; ni++) {
            f32x4 a = acc[mi][ni];
            int col = n0 + wn * 64 + ni * 16 + r16;
            int rbase = m0 + wm * 64 + mi * 16 + quad * 4;
            #pragma unroll
            for (int r = 0; r < 4; r++) {
                int row = rbase + r;
                float v = a[r];
                if (MODE == 0 || MODE == 2 || MODE == 3) v += bias[col];
                if (MODE == 2) v = (v > 20.f) ? v : log1pf(__expf(v));
                if (MODE == 3) v += res[(size_t)row * ldc + col];
                if (MODE == 1) {
                    if (col < 96) C[(size_t)row * 96 + col] = v;
                } else if (MODE == 0) {
                    Cbf[(size_t)row * ldc + col] = __float2bfloat16(v);
                } else {
                    C[(size_t)row * ldc + col] = v;
                }
            }
        }
    }
}

// -------------------------------------------- reduce split-K partials of dbc
__global__ void reduce_dbc_kernel(const float* __restrict__ p, float* __restrict__ dbc,
                                  bf16* __restrict__ dbc_bf) {
    int i = blockIdx.x * 256 + threadIdx.x;      // SEQ*96
    const int SP = SEQ * 96;
    float v = p[i] + p[i + SP] + p[i + 2 * SP] + p[i + 3 * SP];
    dbc[i] = v;
    int row = i / 96, c = i - row * 96;
    if (c < DTRANK) dbc_bf[(size_t)row * DTRANK + c] = __float2bfloat16(v);
}

// --------------------------------------------------- exp-chain detection
__device__ __forceinline__ bool a_is_neg_integers(const float* a) {
    bool fast = true;
    #pragma unroll
    for (int n = 0; n < NSTATE; n++)
        fast = fast && (__builtin_fabsf(a[n] + (float)(n + 1)) < 1e-3f * (n + 1));
    return fast;
}

// ---------------------------------------------------------------------------
// Chunked scan pass 1 — LDS-free (wave-uniform scalar B/C loads, ptr induction)
// ---------------------------------------------------------------------------
__global__ __launch_bounds__(256)
void scan1_kernel(const float* __restrict__ delta, const bf16* __restrict__ u,
                  const float* __restrict__ dbc, const float* __restrict__ A_log,
                  float* __restrict__ h_end, float* __restrict__ dsum) {
    int k = blockIdx.x, d = blockIdx.y * 256 + threadIdx.x;
    int s0 = k * LC;
    float a[NSTATE];
    #pragma unroll
    for (int n = 0; n < NSTATE; n++) a[n] = -__expf(A_log[(size_t)d * NSTATE + n]);
    bool fast = a_is_neg_integers(a);
    const float* dp = delta + (size_t)s0 * DINNER + d;
    const unsigned short* up = (const unsigned short*)u + (size_t)s0 * DINNER + d;
    const float* br = dbc + (size_t)s0 * 96 + DTRANK;   // uniform across block
    float h[NSTATE] = {};
    float ds = 0.f;
    if (fast) {
        #pragma unroll 2
        for (int r = 0; r < LC; r++) {
            float dl = *dp;
            float uu = b2f(*up);
            float4 b0 = *(const float4*)(br);
            float4 b1 = *(const float4*)(br + 4);
            float4 b2 = *(const float4*)(br + 8);
            float4 b3 = *(const float4*)(br + 12);
            float Bv[NSTATE] = {b0.x, b0.y, b0.z, b0.w, b1.x, b1.y, b1.z, b1.w,
                                b2.x, b2.y, b2.z, b2.w, b3.x, b3.y, b3.z, b3.w};
            ds += dl;
            float du = dl * uu;
            float g = __expf(-dl);
            float fac = 1.f;
            #pragma unroll
            for (int n = 0; n < NSTATE; n++) {
                fac *= g;
                h[n] = fac * h[n] + du * Bv[n];
            }
            dp += DINNER; up += DINNER; br += 96;
        }
    } else {
        #pragma unroll 2
        for (int r = 0; r < LC; r++) {
            float dl = *dp;
            float uu = b2f(*up);
            float4 b0 = *(const float4*)(br);
            float4 b1 = *(const float4*)(br + 4);
            float4 b2 = *(const float4*)(br + 8);
            float4 b3 = *(const float4*)(br + 12);
            float Bv[NSTATE] = {b0.x, b0.y, b0.z, b0.w, b1.x, b1.y, b1.z, b1.w,
                                b2.x, b2.y, b2.z, b2.w, b3.x, b3.y, b3.z, b3.w};
            ds += dl;
            float du = dl * uu;
            #pragma unroll
            for (int n = 0; n < NSTATE; n++)
                h[n] = __expf(dl * a[n]) * h[n] + du * Bv[n];
            dp += DINNER; up += DINNER; br += 96;
        }
    }
    #pragma unroll
    for (int n = 0; n < NSTATE; n++)
        h_end[((size_t)k * NSTATE + n) * DINNER + d] = h[n];
    dsum[(size_t)k * DINNER + d] = ds;
}

// ------------------------------------------------------- chunked scan pass 2
__global__ void scan2_kernel(const float* __restrict__ A_log, const float* __restrict__ dsum,
                             const float* __restrict__ h_end, float* __restrict__ hinit) {
    int id = blockIdx.x * 256 + threadIdx.x;     // DINNER*NSTATE
    int d = id & (DINNER - 1), n = id >> 11;
    float a = -__expf(A_log[(size_t)d * NSTATE + n]);
    float h = 0.f;
    #pragma unroll 4
    for (int k = 0; k < NC; k++) {
        size_t off = ((size_t)k * NSTATE + n) * DINNER + d;
        hinit[off] = h;
        h = __expf(a * dsum[(size_t)k * DINNER + d]) * h + h_end[off];
    }
}

// ------------------------------------------- chunked scan pass 3 — LDS-free
__global__ __launch_bounds__(256)
void scan3_kernel(float* __restrict__ delta_y, const bf16* __restrict__ u,
                  const float* __restrict__ dbc, const float* __restrict__ A_log,
                  const float* __restrict__ Dp, const float* __restrict__ hinit) {
    int k = blockIdx.x, d = blockIdx.y * 256 + threadIdx.x;
    int s0 = k * LC;
    float a[NSTATE];
    #pragma unroll
    for (int n = 0; n < NSTATE; n++) a[n] = -__expf(A_log[(size_t)d * NSTATE + n]);
    bool fast = a_is_neg_integers(a);
    float h[NSTATE];
    #pragma unroll
    for (int n = 0; n < NSTATE; n++)
        h[n] = hinit[((size_t)k * NSTATE + n) * DINNER + d];
    float dpv = Dp[d];
    float* dp = delta_y + (size_t)s0 * DINNER + d;
    const unsigned short* up = (const unsigned short*)u + (size_t)s0 * DINNER + d;
    const float* br = dbc + (size_t)s0 * 96 + DTRANK;   // uniform across block
    if (fast) {
        #pragma unroll 2
        for (int r = 0; r < LC; r++) {
            float dl = *dp;
            float uu = b2f(*up);
            float4 b0 = *(const float4*)(br);
            float4 b1 = *(const float4*)(br + 4);
            float4 b2 = *(const float4*)(br + 8);
            float4 b3 = *(const float4*)(br + 12);
            float4 c0 = *(const float4*)(br + 16);
            float4 c1 = *(const float4*)(br + 20);
            float4 c2 = *(const float4*)(br + 24);
            float4 c3 = *(const float4*)(br + 28);
            float Bv[NSTATE] = {b0.x, b0.y, b0.z, b0.w, b1.x, b1.y, b1.z, b1.w,
                                b2.x, b2.y, b2.z, b2.w, b3.x, b3.y, b3.z, b3.w};
            float Cv[NSTATE] = {c0.x, c0.y, c0.z, c0.w, c1.x, c1.y, c1.z, c1.w,
                                c2.x, c2.y, c2.z, c2.w, c3.x, c3.y, c3.z, c3.w};
            float du = dl * uu;
            float g = __expf(-dl);
            float y = uu * dpv;
            float fac = 1.f;
            #pragma unroll
            for (int n = 0; n < NSTATE; n++) {
                fac *= g;
                h[n] = fac * h[n] + du * Bv[n];
                y += h[n] * Cv[n];
            }
            *dp = y;
            dp += DINNER; up += DINNER; br += 96;
        }
    } else {
        #pragma unroll 2
        for (int r = 0; r < LC; r++) {
            float dl = *dp;
            float uu = b2f(*up);
            float4 b0 = *(const float4*)(br);
            float4 b1 = *(const float4*)(br + 4);
            float4 b2 = *(const float4*)(br + 8);
            float4 b3 = *(const float4*)(br + 12);
            float4 c0 = *(const float4*)(br + 16);
            float4 c1 = *(const float4*)(br + 20);
            float4 c2 = *(const float4*)(br + 24);
            float4 c3 = *(const float4*)(br + 28);
            float Bv[NSTATE] = {b0.x, b0.y, b0.z, b0.w, b1.x, b1.y, b1.z, b1.w,
                                b2.x, b2.y, b2.z, b2.w, b3.x, b3.y, b3.z, b3.w};
            float Cv[NSTATE] = {c0.x, c0.y, c0.z, c0.w, c1.x, c1.y, c1.z, c1.w,
                                c2.x, c2.y, c2.z, c2.w, c3.x, c3.y, c3.z, c3.w};
            float du = dl * uu;
            float y = uu * dpv;
            #pragma unroll
            for (int n = 0; n < NSTATE; n++) {
                h[n] = __expf(dl * a[n]) * h[n] + du * Bv[n];
                y += h[n] * Cv[n];
            }
            *dp = y;
            dp += DINNER; up += DINNER; br += 96;
        }
    }
}

// ---------------------------------------------------------------------------
extern "C" void kernel_launch(void* const* d_in, const int* in_sizes, int n_in,
                              void* d_out, int out_size, void* d_ws, size_t ws_size,
                              hipStream_t stream) {
    const float* x         = (const float*)d_in[0];
    const float* pos       = (const float*)d_in[1];
    const float* ln_g      = (const float*)d_in[2];
    const float* ln_b      = (const float*)d_in[3];
    const float* innorm_g  = (const float*)d_in[4];
    const float* innorm_b  = (const float*)d_in[5];
    const float* in_proj_w = (const float*)d_in[6];
    const float* in_proj_b = (const float*)d_in[7];
    const float* conv_w    = (const float*)d_in[8];
    const float* conv_b    = (const float*)d_in[9];
    const float* deltaBC_w = (const float*)d_in[10];
    const float* dt_proj_w = (const float*)d_in[11];
    const float* dt_proj_b = (const float*)d_in[12];
    const float* A_log     = (const float*)d_in[13];
    const float* Dp        = (const float*)d_in[14];
    const float* outnorm_g = (const float*)d_in[15];
    const float* outnorm_b = (const float*)d_in[16];
    const float* out_proj_w= (const float*)d_in[17];
    const float* out_proj_b= (const float*)d_in[18];

    float* enc = (float*)d_out;
    char* ws = (char*)d_ws;
    const size_t MB = 1024 * 1024;
    bf16*  h_bf   = (bf16*) (ws + 0);            //  8 MB [S,d]  (aliased w/ p_bf)
    bf16*  p_bf   = (bf16*) (ws + 0);            // 16 MB [S,di]
    bf16*  xz_bf  = (bf16*) (ws + 16 * MB);      // 32 MB [S,2di]
    float* dlt    = (float*)(ws + 48 * MB);      // 32 MB delta -> y (in place)
    float* dbcp   = (float*)(ws + 48 * MB);      //  6 MB splitK partials (alias dlt)
    bf16*  u_bf   = (bf16*) (ws + 80 * MB);      // 16 MB [S,di]
    float* dbc    = (float*)(ws + 96 * MB);      // 1.5MB [S,96]
    bf16*  dbc_bf = (bf16*) (ws + 98 * MB);      // 0.5MB [S,64]
    float* h_end  = (float*)(ws + 99 * MB);      //  8 MB [NC,n,di]
    float* hinit  = (float*)(ws + 107 * MB);     //  8 MB [NC,n,di]
    float* dsum   = (float*)(ws + 115 * MB);     // 0.5MB [NC,di]
    bf16*  w_in   = (bf16*) (ws + 116 * MB);     // 32 MB (4 layers x 8)
    bf16*  w_out  = (bf16*) (ws + 148 * MB);     // 16 MB (4 x 4)
    bf16*  w_dbc  = (bf16*) (ws + 164 * MB);     // 1.5 MB (4 x .375)
    bf16*  w_dt   = (bf16*) (ws + 166 * MB);     //  1 MB (4 x .25) -> 167 MB total

    // weight conversion for ALL layers, one dispatch
    cvt4_kernel<<<(S0 + S1 + S2 + S3) / 1024, 256, 0, stream>>>(
        in_proj_w, out_proj_w, deltaBC_w, dt_proj_w, w_in, w_out, w_dbc, w_dt);

    ln_kernel<DMODEL, float><<<SEQ, 256, 0, stream>>>(x, pos, ln_g, ln_b, enc, 1e-6f);

    for (int L = 0; L < NLAYERS; L++) {
        const float* Al  = A_log + (size_t)L * DINNER * NSTATE;
        const float* Dpl = Dp + (size_t)L * DINNER;

        ln_kernel<DMODEL, bf16><<<SEQ, 256, 0, stream>>>(enc, nullptr, innorm_g + L * DMODEL,
                                                         innorm_b + L * DMODEL, h_bf, 1e-5f);
        // xz = h @ in_proj_w^T + b  -> bf16   [4096 x 4096], K=1024
        mfma_gemm<0><<<dim3(32, 32), 256, 0, stream>>>(
            h_bf, DMODEL, w_in + (size_t)L * CN0, DMODEL, in_proj_b + (size_t)L * 2 * DINNER,
            nullptr, 2 * DINNER, nullptr, xz_bf, SEQ, 2 * DINNER, DMODEL);
        conv_kernel<<<(SEQ * 512) / 256, 256, 0, stream>>>(
            xz_bf, conv_w + (size_t)L * DINNER * 3, conv_b + L * DINNER, u_bf);
        // dbc = u @ deltaBC_w^T   split-K x4, K=512 each
        mfma_gemm<1><<<dim3(32, 1, 4), 256, 0, stream>>>(
            u_bf, DINNER, w_dbc + (size_t)L * CN2, DINNER, nullptr,
            dbcp, 96, nullptr, nullptr, SEQ, 96, 512);
        reduce_dbc_kernel<<<(SEQ * 96) / 256, 256, 0, stream>>>(dbcp, dbc, dbc_bf);
        // delta = softplus(dbc[:,:64] @ dt_proj_w^T + b)   [4096 x 2048], K=64
        mfma_gemm<2><<<dim3(32, 16), 256, 0, stream>>>(
            dbc_bf, DTRANK, w_dt + (size_t)L * CN3, DTRANK, dt_proj_b + L * DINNER,
            dlt, DINNER, nullptr, nullptr, SEQ, DINNER, DTRANK);
        // selective scan, 3-pass chunked; y overwrites dlt
        scan1_kernel<<<dim3(NC, DINNER / 256), 256, 0, stream>>>(dlt, u_bf, dbc, Al, h_end, dsum);
        scan2_kernel<<<(DINNER * NSTATE) / 256, 256, 0, stream>>>(Al, dsum, h_end, hinit);
        scan3_kernel<<<dim3(NC, DINNER / 256), 256, 0, stream>>>(dlt, u_bf, dbc, Al,
                                                                 Dpl, hinit);
        outnorm_silu_kernel<<<SEQ, 256, 0, stream>>>(dlt, xz_bf, outnorm_g + L * DINNER,
                                                     outnorm_b + L * DINNER, p_bf, 1e-5f);
        // enc = p @ out_proj_w^T + b + enc   [4096 x 1024], K=2048
        mfma_gemm<3><<<dim3(32, 8), 256, 0, stream>>>(
            p_bf, DINNER, w_out + (size_t)L * CN1, DINNER, out_proj_b + L * DMODEL,
            enc, DMODEL, enc, nullptr, SEQ, DMODEL, DINNER);
    }
}